// Round 12
// baseline (446.670 us; speedup 1.0000x reference)
//
#include <hip/hip_runtime.h>

// Soft-DTW (gamma=1), batched 64 x (1024 vs 1024, 2-D points).
//
// === R12: 2 waves/SIMD + contour prefetch ===
// R11 (256 blocks x 4 waves, K=16, relaxed-agent handoff) = 341us, absmax 0.
// Decomposition: 5730 cyc/epoch, ~1520 issue (VALUBusy 26.6% device-wide at
// 1 wave/SIMD) -- the rest is exposed latency nothing can hide: f64 chain
// bubbles (~700), handoff vmcnt-drain + reader poll (~1000), and
// compute_k2's 16 global contour loads at epoch bottom (~2000, unhidden at
// 1 wave/SIMD). Changes, protocol otherwise byte-identical to R11:
//  1. PARTS=2, WPB=8, TPB=512, 128 blocks: same 16-wave global pipeline,
//     now 2 waves/SIMD -> chain/poll/load stalls interleave across waves.
//     Cross-block boundaries drop 3->1 per batch (rest in LDS ring);
//     handoff partners (blockIdx b, 64+b) share an XCD under %8 dispatch.
//  2. Contour prefetched at epoch TOP into registers (cwb[16]); k2
//     conversion at epoch bottom is pure VALU -> load latency hides under
//     the chain even where TLP is thin.
//  3. Publish split: value stores before rescale; vmcnt(0)+flag after it
//     (drain overlaps the rescale).
//
// Core (verified absmax 0.0 since R8): exp2-domain Z = 2^(off - R*log2e);
//   Z_d[i] = 2^(-D*log2e) * (Zdiag + Zup + Zleft)
// chain = add+add+mul (f64) + DPP shift + selects, zero transcendentals
// on-chain; per-wave exact power-of-2 rescale per epoch (DPP max-reduce);
// lane-0 neighbor values converted by exact 2^(off-oin) two-stage factors;
// global wave w = part*WPB + wl runs K diagonals behind wave w-1; one
// __syncthreads per epoch; intra-block boundary via LDS parity ring;
// cross-block via RELAXED agent-scope atomics (no cache maintenance):
// writer stores K+1 values -> vmcnt(0) -> flag=g; reader polls flag>=need
// at epoch bottom (prefetch, hidden under barrier), compiler barrier, loads.
// Writer-finished epochs (need > WLAST) zero-fill: those values feed only
// inactive cells (k2=0 -> zn=0). Final cell snapshotted at its own step;
// R = (res_off - log2(res)) * ln2; one atomicAdd per batch.

#define N 1024
#define PARTS 2
#define TPB 512
#define WPB 8                                  // waves per block
#define NW_G (PARTS * WPB)                     // 16 global waves
#define K 16                                   // diagonals per epoch
#define TOTAL (2 * N - 3 + (NW_G - 1) * K)     // 2045 + 240 = 2285 steps
#define NGRP ((TOTAL + K - 1) / K)             // 143 epochs
#define SLOTS 8                                // cross-block ring depth
#define NBND (PARTS - 1)                       // 1 boundary per batch
#define L2E 1.442695040888963f
#define LN2D 0.6931471805599453

// workspace: vals[64][NBND][SLOTS][K+1] int64, then flags[64][NBND] int64
#define VALS_LL (64 * NBND * SLOTS * (K + 1))
#define WS_BYTES (VALS_LL * 8 + 64 * NBND * 8)

__device__ __forceinline__ float sqdist2(float2 a, float2 b) {
    float dx = a.x - b.x;
    float dy = a.y - b.y;
    return dx * dx + dy * dy;
}

// 64-bit DPP move (two 32-bit halves, same lane pattern; invalid lanes -> 0).
template <int CTRL>
__device__ __forceinline__ double dpp_movd(double src) {
    long long s = __double_as_longlong(src);
    int lo = __builtin_amdgcn_update_dpp(0, (int)(s & 0xffffffffLL),
                                         CTRL, 0xF, 0xF, false);
    int hi = __builtin_amdgcn_update_dpp(0, (int)(s >> 32),
                                         CTRL, 0xF, 0xF, false);
    return __longlong_as_double(((long long)hi << 32) | (unsigned int)lo);
}

template <int CTRL>
__device__ __forceinline__ int dpp_maxstep(int x) {
    int s = __builtin_amdgcn_update_dpp(0, x, CTRL, 0xF, 0xF, false);
    return max(x, s);
}

// Full 64-lane max of a nonneg int, pure VALU (no LDS); result wave-uniform.
__device__ __forceinline__ int wave_max_i(int x) {
    x = dpp_maxstep<0x111>(x);   // row_shr:1
    x = dpp_maxstep<0x112>(x);   // row_shr:2
    x = dpp_maxstep<0x114>(x);   // row_shr:4
    x = dpp_maxstep<0x118>(x);   // row_shr:8
    x = dpp_maxstep<0x142>(x);   // row_bcast15
    x = dpp_maxstep<0x143>(x);   // row_bcast31
    return __builtin_amdgcn_readlane(x, 63);
}

// exact 2^s as double for s in [-1022, 1023]
__device__ __forceinline__ double pow2d(int s) {
    return __longlong_as_double((long long)(1023 + s) << 52);
}

__global__ __launch_bounds__(TPB, 2) void dtw_kernel(
    const float2* __restrict__ snake,
    const float2* __restrict__ contour,
    float* __restrict__ out,
    long long* __restrict__ wsv,
    long long* __restrict__ wsf)
{
    const int t    = threadIdx.x;
    const int lane = t & 63;
    const int wl   = t >> 6;                 // local wave 0..7
    const int part = blockIdx.x >> 6;        // part-major: writers first
    const int b    = blockIdx.x & 63;        // batch
    const int w    = part * WPB + wl;        // global wave 0..15
    const int i    = (w << 6) + lane;        // global DP row

    __shared__ double ringv[WPB][2][K];      // intra-block boundary ring
    __shared__ int    ringo[WPB][2];
    __shared__ float  initvals[3];           // R0[0], R1[0], R1[1]

    const float2* sg = snake   + (size_t)b * N;
    const float2* cg = contour + (size_t)b * N;
    const float2 sp = sg[i];                 // snake point: register-resident

    if (t < WPB * 2 * K) ((double*)ringv)[t] = 0.0;   // Z(INF) = 0
    if (t < WPB * 2)     ((int*)ringo)[t] = 0;
    if (part == 0 && t == 0) {
        // Diagonals 0 and 1 (reference `init`):
        float2 s0 = sg[0], s1 = sg[1], c0 = cg[0], c1 = cg[1];
        float d00 = sqdist2(s0, c0);
        initvals[0] = d00;
        initvals[1] = sqdist2(s0, c1) + d00;
        initvals[2] = sqdist2(s1, c0) + d00;
    }
    __syncthreads();

    // Z-state entering the wave's first executed step (off = 0):
    double cur = 0.0, nb1 = 0.0, nb2 = 0.0;
    int off = 0;
    bool adopted = (w == 0);
    if (part == 0) {
        if (t == 0) {
            cur = (double)__builtin_amdgcn_exp2f(-L2E * initvals[1]);
        } else if (t == 1) {
            cur = (double)__builtin_amdgcn_exp2f(-L2E * initvals[2]);
            nb1 = (double)__builtin_amdgcn_exp2f(-L2E * initvals[1]);
            nb2 = (double)__builtin_amdgcn_exp2f(-L2E * initvals[0]);
        } else if (t == 2) {
            nb1 = (double)__builtin_amdgcn_exp2f(-L2E * initvals[2]);
        }
    }

    double res = 1.0;                        // final-cell snapshot (my row)
    int res_off = 0;

    const int lo = (w == 0) ? 2 : (64 * w - 1);   // -1 pre-step seeds nb1
    const int hi = 64 * w + 63 + (N - 1);
    // Writer (wave w-1) last publishing epoch.
    const int WLAST = (w > 0) ? ((64 * (w - 1) + 1084) / K + (w - 1)) : 0;
    int d0 = 2 - K * w;

    double k2[K], rvc[K], wb[K];
    #pragma unroll
    for (int k = 0; k < K; ++k) rvc[k] = 0.0;
    double vr_p[K];                          // cross-block prefetch (lane 0)
    #pragma unroll
    for (int k = 0; k < K; ++k) vr_p[k] = 0.0;
    int oin_p = 0;

    const long long* vin =
        wsv + ((size_t)b * NBND + (part - 1)) * SLOTS * (K + 1);
    long long* vout =
        wsv + ((size_t)b * NBND + part) * SLOTS * (K + 1);
    const long long* fin = wsf + (b * NBND + (part - 1));
    long long* fout = wsf + (b * NBND + part);

    // Epoch-0 factors (prologue; cold loads acceptable once).
    #pragma unroll
    for (int k = 0; k < K; ++k) {
        const unsigned u = (unsigned)(d0 + k - i);
        float2 c = cg[u & (N - 1)];
        float dx = sp.x - c.x, dy = sp.y - c.y;
        float e = __builtin_amdgcn_exp2f((dx * dx + dy * dy) * (-L2E));
        k2[k] = (u < (unsigned)N) ? (double)e : 0.0;
    }

    for (int g = 0; g < NGRP; ++g) {
        // Epoch TOP: issue contour loads for NEXT epoch's factors (consumed
        // at epoch bottom -> latency hidden under the chain).
        float2 cwb[K];
        #pragma unroll
        for (int k = 0; k < K; ++k)
            cwb[k] = cg[(unsigned)(d0 + K + k - i) & (N - 1)];

        const bool overlap = (d0 <= hi) && (d0 + (K - 1) >= lo);
        if (overlap) {
            if (w > 0) {
                int oin;
                if (wl > 0) {
                    const int p = (g ^ 1) & 1;
                    oin = ringo[wl - 1][p];                // all lanes (LDS)
                    if (!adopted) { off = oin; adopted = true; }
                    if (lane == 0) {
                        int dl = off - oin;
                        int c1 = min(max(dl, -1022), 1022);
                        int c2 = min(max(dl - c1, -1022), 1022);
                        double f1 = pow2d(c1), f2 = pow2d(c2);
                        const double* q = &ringv[wl - 1][p][0];
                        #pragma unroll
                        for (int k = 0; k < K; ++k)
                            rvc[k] = (q[k] * f1) * f2;
                    }
                } else {
                    int tmp = (lane == 0) ? oin_p : 0;
                    oin = __builtin_amdgcn_readlane(tmp, 0);  // broadcast
                    if (!adopted) { off = oin; adopted = true; }
                    if (lane == 0) {
                        int dl = off - oin;
                        int c1 = min(max(dl, -1022), 1022);
                        int c2 = min(max(dl - c1, -1022), 1022);
                        double f1 = pow2d(c1), f2 = pow2d(c2);
                        #pragma unroll
                        for (int k = 0; k < K; ++k)
                            rvc[k] = (vr_p[k] * f1) * f2;
                    }
                }
            }

            const int kres = (i + N - 1) - d0;   // step of my row's last cell

            // The chain: add+add+mul (f64) + DPP + selects per step.
            #pragma unroll
            for (int k = 0; k < K; ++k) {
                double zn = k2[k] * ((nb2 + nb1) + cur);
                wb[k] = zn;
                if (k == kres) { res = zn; res_off = off; }
                cur = zn;
                double a  = dpp_movd<0x111>(zn);   // row_shr:1
                double bc = dpp_movd<0x142>(zn);   // row_bcast15
                double up = ((lane & 15) == 0) ? bc : a;
                nb2 = nb1;
                nb1 = (lane == 0) ? rvc[k] : up;
            }

            // Boundary publish part 1: value stores (pre-rescale off).
            if (lane == 63) {
                if (wl < WPB - 1) {
                    #pragma unroll
                    for (int k = 0; k < K; ++k) ringv[wl][g & 1][k] = wb[k];
                    ringo[wl][g & 1] = off;
                } else if (part < PARTS - 1) {
                    // RELAXED agent stores (LLC-coherent, no cache maint.)
                    long long* q = vout + (size_t)(g & (SLOTS - 1)) * (K + 1);
                    #pragma unroll
                    for (int k = 0; k < K; ++k)
                        __hip_atomic_store(q + k, __double_as_longlong(wb[k]),
                                           __ATOMIC_RELAXED,
                                           __HIP_MEMORY_SCOPE_AGENT);
                    __hip_atomic_store(q + K, (long long)off,
                                       __ATOMIC_RELAXED,
                                       __HIP_MEMORY_SCOPE_AGENT);
                }
            }

            // Per-wave exact power-of-2 rescale (DPP max-reduce, no LDS);
            // overlaps the store drain.
            int e = (int)((__double_as_longlong(cur) >> 52) & 0x7FF);
            e = wave_max_i(e);
            if (e > 0) {
                int sh = 1023 - e;
                int c1 = min(max(sh, -1022), 1022);
                int c2 = min(max(sh - c1, -1022), 1022);
                double f1 = pow2d(c1), f2 = pow2d(c2);
                cur = (cur * f1) * f2;
                nb1 = (nb1 * f1) * f2;
                nb2 = (nb2 * f1) * f2;
                off += sh;
            }

            // Boundary publish part 2: drain + flag (after rescale).
            if (lane == 63 && wl == WPB - 1 && part < PARTS - 1) {
                asm volatile("s_waitcnt vmcnt(0)" ::: "memory");
                __hip_atomic_store(fout, (long long)g, __ATOMIC_RELAXED,
                                   __HIP_MEMORY_SCOPE_AGENT);
            }
        }

        d0 += K;

        // Epoch BOTTOM: convert prefetched contour to k2 (pure VALU).
        #pragma unroll
        for (int k = 0; k < K; ++k) {
            const unsigned u = (unsigned)(d0 + k - i);
            float dx = sp.x - cwb[k].x, dy = sp.y - cwb[k].y;
            float e = __builtin_amdgcn_exp2f((dx * dx + dy * dy) * (-L2E));
            k2[k] = (u < (unsigned)N) ? (double)e : 0.0;
        }

        // Cross-block PREFETCH for epoch g+1 (poll+read at epoch bottom).
        if (wl == 0 && w > 0) {
            const bool nov = (d0 <= hi) && (d0 + (K - 1) >= lo);
            if (nov && lane == 0) {
                const int need = g;           // = (g+1) - 1
                if (need > WLAST) {
                    // Writer finished: values feed only inactive cells.
                    #pragma unroll
                    for (int k = 0; k < K; ++k) vr_p[k] = 0.0;
                    oin_p = off;              // zeros are offset-immune
                } else {
                    while (__hip_atomic_load(fin, __ATOMIC_RELAXED,
                                             __HIP_MEMORY_SCOPE_AGENT)
                           < (long long)need)
                        __builtin_amdgcn_s_sleep(2);
                    asm volatile("" ::: "memory");   // no hoist past poll
                    const long long* q =
                        vin + (size_t)(need & (SLOTS - 1)) * (K + 1);
                    #pragma unroll
                    for (int k = 0; k < K; ++k)
                        vr_p[k] = __longlong_as_double(
                            __hip_atomic_load(q + k, __ATOMIC_RELAXED,
                                              __HIP_MEMORY_SCOPE_AGENT));
                    oin_p = (int)__hip_atomic_load(q + K, __ATOMIC_RELAXED,
                                                   __HIP_MEMORY_SCOPE_AGENT);
                }
            }
        }

        __syncthreads();
    }

    // Global row 1023 lives in part 1, t 511: res = Z of R[1023,1023].
    if (part == PARTS - 1 && t == TPB - 1) {
        double R = ((double)res_off - log2(res)) * LN2D;
        atomicAdd(out, (float)(R * (1.0 / 64.0)));
    }
}

extern "C" void kernel_launch(void* const* d_in, const int* in_sizes, int n_in,
                              void* d_out, int out_size, void* d_ws, size_t ws_size,
                              hipStream_t stream) {
    const float2* snake   = (const float2*)d_in[0];
    const float2* contour = (const float2*)d_in[1];
    float* out = (float*)d_out;
    // Harness re-poisons d_out to 0xAA before every timed launch.
    hipMemsetAsync(out, 0, sizeof(float), stream);
    // Cross-block flags must start at -1 (0xFF...) every launch.
    hipMemsetAsync(d_ws, 0xFF, WS_BYTES, stream);
    long long* wsv = (long long*)d_ws;
    long long* wsf = (long long*)((char*)d_ws + (size_t)VALS_LL * 8);
    dtw_kernel<<<PARTS * 64, TPB, 0, stream>>>(snake, contour, out, wsv, wsf);
}

// Round 13
// 425.439 us; speedup vs baseline: 1.0499x; 1.0499x over previous
//
#include <hip/hip_runtime.h>

// Soft-DTW (gamma=1), batched 64 x (1024 vs 1024, 2-D points).
//
// === R13: R11 geometry (all 256 CUs) + contour prefetch + extra x-block skew ===
// R12 taught: 128 blocks = only 128 CUs busy (per-CU issue x2) -> regression;
// with 1024 total waves, per-SIMD TLP is capped at 1, so keep 256 blocks x 4
// waves (R11, 341us) and attack the serial per-epoch costs instead:
//  1. Contour register-prefetch (validated in R12): loads for the NEXT
//     epoch's k2 issued at epoch TOP, converted (pure VALU) at epoch BOTTOM
//     -> ~16 global-load latencies off the critical path.
//  2. Publish split (validated in R12): boundary value stores before the
//     rescale, vmcnt(0)+flag after it -> drain overlaps the rescale.
//  3. NEW: extra cross-block skew XK=K. R11's reader needed the writer's
//     epoch-(g-1) publish at its epoch-g top (zero slack -> spin + exposed
//     drain). With skew K+XK=2K at the 3 cross-block boundaries, the reader
//     consumes epoch g-2: one full epoch of slack, handoff fully pipelined.
//     Cost: 48 extra steps, NGRP 143->146 (+2%).
//
// Core (verified absmax 0.0 since R8): exp2-domain Z = 2^(off - R*log2e);
//   Z_d[i] = 2^(-D*log2e) * (Zdiag + Zup + Zleft)
// chain = add+add+mul (f64) + DPP shift + selects, zero transcendentals
// on-chain; per-wave exact power-of-2 rescale per epoch (DPP max-reduce);
// lane-0 neighbor values converted by exact 2^(off-oin) two-stage factors;
// wave w skew s_w = K*w + XK*part; one __syncthreads per epoch; intra-block
// boundary via LDS parity ring (skew K: reader epoch g uses writer epoch
// g-1, parity (g^1)&1); cross-block via RELAXED agent-scope atomics (LLC-
// coherent, no cache maintenance): writer stores K+1 values -> vmcnt(0) ->
// flag=g; reader prefetches at epoch-g bottom with need=g-1, poll flag>=
// need, compiler barrier, relaxed loads. Writer-finished epochs (need >
// WLAST) zero-fill: those values feed only inactive cells (k2=0 -> zn=0).
// Final cell snapshotted at its own step; R = (res_off - log2(res)) * ln2.

#define N 1024
#define PARTS 4
#define TPB 256
#define WPB 4                                  // waves per block
#define NW_G (PARTS * WPB)                     // 16 global waves
#define K 16                                   // diagonals per epoch
#define XK 16                                  // extra skew per x-block bnd
#define SLOTS 8                                // cross-block ring depth
#define NBND (PARTS - 1)                       // 3 boundaries per batch
// last wave w=15: g_max = (64*15+1086 + K*15 + XK*3 - 2)/K -> +1 epochs
#define NGRP ((64 * (NW_G - 1) + 1084 + K * (NW_G - 1) + XK * (PARTS - 1)) / K + 1)
#define L2E 1.442695040888963f
#define LN2D 0.6931471805599453

// workspace: vals[64][NBND][SLOTS][K+1] int64, then flags[64][NBND] int64
#define VALS_LL (64 * NBND * SLOTS * (K + 1))
#define WS_BYTES (VALS_LL * 8 + 64 * NBND * 8)

__device__ __forceinline__ float sqdist2(float2 a, float2 b) {
    float dx = a.x - b.x;
    float dy = a.y - b.y;
    return dx * dx + dy * dy;
}

// 64-bit DPP move (two 32-bit halves, same lane pattern; invalid lanes -> 0).
template <int CTRL>
__device__ __forceinline__ double dpp_movd(double src) {
    long long s = __double_as_longlong(src);
    int lo = __builtin_amdgcn_update_dpp(0, (int)(s & 0xffffffffLL),
                                         CTRL, 0xF, 0xF, false);
    int hi = __builtin_amdgcn_update_dpp(0, (int)(s >> 32),
                                         CTRL, 0xF, 0xF, false);
    return __longlong_as_double(((long long)hi << 32) | (unsigned int)lo);
}

template <int CTRL>
__device__ __forceinline__ int dpp_maxstep(int x) {
    int s = __builtin_amdgcn_update_dpp(0, x, CTRL, 0xF, 0xF, false);
    return max(x, s);
}

// Full 64-lane max of a nonneg int, pure VALU (no LDS); result wave-uniform.
__device__ __forceinline__ int wave_max_i(int x) {
    x = dpp_maxstep<0x111>(x);   // row_shr:1
    x = dpp_maxstep<0x112>(x);   // row_shr:2
    x = dpp_maxstep<0x114>(x);   // row_shr:4
    x = dpp_maxstep<0x118>(x);   // row_shr:8
    x = dpp_maxstep<0x142>(x);   // row_bcast15
    x = dpp_maxstep<0x143>(x);   // row_bcast31
    return __builtin_amdgcn_readlane(x, 63);
}

// exact 2^s as double for s in [-1022, 1023]
__device__ __forceinline__ double pow2d(int s) {
    return __longlong_as_double((long long)(1023 + s) << 52);
}

__global__ __launch_bounds__(TPB) void dtw_kernel(
    const float2* __restrict__ snake,
    const float2* __restrict__ contour,
    float* __restrict__ out,
    long long* __restrict__ wsv,
    long long* __restrict__ wsf)
{
    const int t    = threadIdx.x;
    const int lane = t & 63;
    const int wl   = t >> 6;                 // local wave 0..3
    const int part = blockIdx.x >> 6;        // part-major: writers first
    const int b    = blockIdx.x & 63;        // batch
    const int w    = part * WPB + wl;        // global wave 0..15
    const int i    = (w << 6) + lane;        // global DP row

    __shared__ double ringv[WPB][2][K];      // intra-block boundary ring
    __shared__ int    ringo[WPB][2];
    __shared__ float  initvals[3];           // R0[0], R1[0], R1[1]

    const float2* sg = snake   + (size_t)b * N;
    const float2* cg = contour + (size_t)b * N;
    const float2 sp = sg[i];                 // snake point: register-resident

    if (t < WPB * 2 * K) ((double*)ringv)[t] = 0.0;   // Z(INF) = 0
    if (t < WPB * 2)     ((int*)ringo)[t] = 0;
    if (part == 0 && t == 0) {
        // Diagonals 0 and 1 (reference `init`):
        float2 s0 = sg[0], s1 = sg[1], c0 = cg[0], c1 = cg[1];
        float d00 = sqdist2(s0, c0);
        initvals[0] = d00;
        initvals[1] = sqdist2(s0, c1) + d00;
        initvals[2] = sqdist2(s1, c0) + d00;
    }
    __syncthreads();

    // Z-state entering the wave's first executed step (off = 0):
    double cur = 0.0, nb1 = 0.0, nb2 = 0.0;
    int off = 0;
    bool adopted = (w == 0);
    if (part == 0) {
        if (t == 0) {
            cur = (double)__builtin_amdgcn_exp2f(-L2E * initvals[1]);
        } else if (t == 1) {
            cur = (double)__builtin_amdgcn_exp2f(-L2E * initvals[2]);
            nb1 = (double)__builtin_amdgcn_exp2f(-L2E * initvals[1]);
            nb2 = (double)__builtin_amdgcn_exp2f(-L2E * initvals[0]);
        } else if (t == 2) {
            nb1 = (double)__builtin_amdgcn_exp2f(-L2E * initvals[2]);
        }
    }

    double res = 1.0;                        // final-cell snapshot (my row)
    int res_off = 0;

    const int lo = (w == 0) ? 2 : (64 * w - 1);   // -1 pre-step seeds nb1
    const int hi = 64 * w + 63 + (N - 1);
    // Writer (global wave w-1, in part-1 for the cross-block case):
    // its last publishing epoch, including ITS skew.
    const int WLAST = (w > 0)
        ? ((64 * (w - 1) + 1084 + K * (w - 1) + XK * (part - 1)) / K) : 0;
    int d0 = 2 - (K * w + XK * part);        // skew: K/wave + XK/boundary

    double k2[K], rvc[K], wb[K];
    #pragma unroll
    for (int k = 0; k < K; ++k) rvc[k] = 0.0;
    double vr_p[K];                          // cross-block prefetch (lane 0)
    #pragma unroll
    for (int k = 0; k < K; ++k) vr_p[k] = 0.0;
    int oin_p = 0;

    const long long* vin =
        wsv + ((size_t)b * NBND + (part - 1)) * SLOTS * (K + 1);
    long long* vout =
        wsv + ((size_t)b * NBND + part) * SLOTS * (K + 1);
    const long long* fin = wsf + (b * NBND + (part - 1));
    long long* fout = wsf + (b * NBND + part);

    // Epoch-0 factors (prologue; cold loads acceptable once).
    #pragma unroll
    for (int k = 0; k < K; ++k) {
        const unsigned u = (unsigned)(d0 + k - i);
        float2 c = cg[u & (N - 1)];
        float dx = sp.x - c.x, dy = sp.y - c.y;
        float e = __builtin_amdgcn_exp2f((dx * dx + dy * dy) * (-L2E));
        k2[k] = (u < (unsigned)N) ? (double)e : 0.0;
    }

    for (int g = 0; g < NGRP; ++g) {
        // Epoch TOP: issue contour loads for NEXT epoch's factors (consumed
        // at epoch bottom -> latency hidden under the chain).
        float2 cwb[K];
        #pragma unroll
        for (int k = 0; k < K; ++k)
            cwb[k] = cg[(unsigned)(d0 + K + k - i) & (N - 1)];

        const bool overlap = (d0 <= hi) && (d0 + (K - 1) >= lo);
        if (overlap) {
            if (w > 0) {
                int oin;
                if (wl > 0) {
                    const int p = (g ^ 1) & 1;
                    oin = ringo[wl - 1][p];                // all lanes (LDS)
                    if (!adopted) { off = oin; adopted = true; }
                    if (lane == 0) {
                        int dl = off - oin;
                        int c1 = min(max(dl, -1022), 1022);
                        int c2 = min(max(dl - c1, -1022), 1022);
                        double f1 = pow2d(c1), f2 = pow2d(c2);
                        const double* q = &ringv[wl - 1][p][0];
                        #pragma unroll
                        for (int k = 0; k < K; ++k)
                            rvc[k] = (q[k] * f1) * f2;
                    }
                } else {
                    int tmp = (lane == 0) ? oin_p : 0;
                    oin = __builtin_amdgcn_readlane(tmp, 0);  // broadcast
                    if (!adopted) { off = oin; adopted = true; }
                    if (lane == 0) {
                        int dl = off - oin;
                        int c1 = min(max(dl, -1022), 1022);
                        int c2 = min(max(dl - c1, -1022), 1022);
                        double f1 = pow2d(c1), f2 = pow2d(c2);
                        #pragma unroll
                        for (int k = 0; k < K; ++k)
                            rvc[k] = (vr_p[k] * f1) * f2;
                    }
                }
            }

            const int kres = (i + N - 1) - d0;   // step of my row's last cell

            // The chain: add+add+mul (f64) + DPP + selects per step.
            #pragma unroll
            for (int k = 0; k < K; ++k) {
                double zn = k2[k] * ((nb2 + nb1) + cur);
                wb[k] = zn;
                if (k == kres) { res = zn; res_off = off; }
                cur = zn;
                double a  = dpp_movd<0x111>(zn);   // row_shr:1
                double bc = dpp_movd<0x142>(zn);   // row_bcast15
                double up = ((lane & 15) == 0) ? bc : a;
                nb2 = nb1;
                nb1 = (lane == 0) ? rvc[k] : up;
            }

            // Boundary publish part 1: value stores (pre-rescale off).
            if (lane == 63) {
                if (wl < WPB - 1) {
                    #pragma unroll
                    for (int k = 0; k < K; ++k) ringv[wl][g & 1][k] = wb[k];
                    ringo[wl][g & 1] = off;
                } else if (part < PARTS - 1) {
                    // RELAXED agent stores (LLC-coherent, no cache maint.)
                    long long* q = vout + (size_t)(g & (SLOTS - 1)) * (K + 1);
                    #pragma unroll
                    for (int k = 0; k < K; ++k)
                        __hip_atomic_store(q + k, __double_as_longlong(wb[k]),
                                           __ATOMIC_RELAXED,
                                           __HIP_MEMORY_SCOPE_AGENT);
                    __hip_atomic_store(q + K, (long long)off,
                                       __ATOMIC_RELAXED,
                                       __HIP_MEMORY_SCOPE_AGENT);
                }
            }

            // Per-wave exact power-of-2 rescale (DPP max-reduce, no LDS);
            // overlaps the store drain.
            int e = (int)((__double_as_longlong(cur) >> 52) & 0x7FF);
            e = wave_max_i(e);
            if (e > 0) {
                int sh = 1023 - e;
                int c1 = min(max(sh, -1022), 1022);
                int c2 = min(max(sh - c1, -1022), 1022);
                double f1 = pow2d(c1), f2 = pow2d(c2);
                cur = (cur * f1) * f2;
                nb1 = (nb1 * f1) * f2;
                nb2 = (nb2 * f1) * f2;
                off += sh;
            }

            // Boundary publish part 2: drain + flag (after rescale).
            if (lane == 63 && wl == WPB - 1 && part < PARTS - 1) {
                asm volatile("s_waitcnt vmcnt(0)" ::: "memory");
                __hip_atomic_store(fout, (long long)g, __ATOMIC_RELAXED,
                                   __HIP_MEMORY_SCOPE_AGENT);
            }
        }

        d0 += K;

        // Epoch BOTTOM: convert prefetched contour to k2 (pure VALU).
        #pragma unroll
        for (int k = 0; k < K; ++k) {
            const unsigned u = (unsigned)(d0 + k - i);
            float dx = sp.x - cwb[k].x, dy = sp.y - cwb[k].y;
            float e = __builtin_amdgcn_exp2f((dx * dx + dy * dy) * (-L2E));
            k2[k] = (u < (unsigned)N) ? (double)e : 0.0;
        }

        // Cross-block PREFETCH for epoch g+1. With XK=K extra skew the
        // reader consumes the writer's epoch (g+1)-2 = g-1: one full epoch
        // of slack -> the poll should almost never spin.
        if (wl == 0 && w > 0) {
            const bool nov = (d0 <= hi) && (d0 + (K - 1) >= lo);
            if (nov && lane == 0) {
                const int need = g - 1;
                if (need > WLAST) {
                    // Writer finished: values feed only inactive cells.
                    #pragma unroll
                    for (int k = 0; k < K; ++k) vr_p[k] = 0.0;
                    oin_p = off;              // zeros are offset-immune
                } else {
                    while (__hip_atomic_load(fin, __ATOMIC_RELAXED,
                                             __HIP_MEMORY_SCOPE_AGENT)
                           < (long long)need)
                        __builtin_amdgcn_s_sleep(2);
                    asm volatile("" ::: "memory");   // no hoist past poll
                    const long long* q =
                        vin + (size_t)(need & (SLOTS - 1)) * (K + 1);
                    #pragma unroll
                    for (int k = 0; k < K; ++k)
                        vr_p[k] = __longlong_as_double(
                            __hip_atomic_load(q + k, __ATOMIC_RELAXED,
                                              __HIP_MEMORY_SCOPE_AGENT));
                    oin_p = (int)__hip_atomic_load(q + K, __ATOMIC_RELAXED,
                                                   __HIP_MEMORY_SCOPE_AGENT);
                }
            }
        }

        __syncthreads();
    }

    // Global row 1023 lives in part 3, t 255: res = Z of R[1023,1023].
    if (part == PARTS - 1 && t == TPB - 1) {
        double R = ((double)res_off - log2(res)) * LN2D;
        atomicAdd(out, (float)(R * (1.0 / 64.0)));
    }
}

extern "C" void kernel_launch(void* const* d_in, const int* in_sizes, int n_in,
                              void* d_out, int out_size, void* d_ws, size_t ws_size,
                              hipStream_t stream) {
    const float2* snake   = (const float2*)d_in[0];
    const float2* contour = (const float2*)d_in[1];
    float* out = (float*)d_out;
    // Harness re-poisons d_out to 0xAA before every timed launch.
    hipMemsetAsync(out, 0, sizeof(float), stream);
    // Cross-block flags must start at -1 (0xFF...) every launch.
    hipMemsetAsync(d_ws, 0xFF, WS_BYTES, stream);
    long long* wsv = (long long*)d_ws;
    long long* wsf = (long long*)((char*)d_ws + (size_t)VALS_LL * 8);
    dtw_kernel<<<PARTS * 64, TPB, 0, stream>>>(snake, contour, out, wsv, wsf);
}